// Round 1
// 285.005 us; speedup vs baseline: 1.0738x; 1.0738x over previous
//
#include <hip/hip_runtime.h>
#include <cstdint>
#include <math.h>

#define B_ 64
#define S_ 512
#define H_ 1024
#define T_ 24
#define TP_ 32   // W padded to 32 rows (zeros) so B-fragment loads never go OOB

typedef unsigned int u32;
typedef unsigned short u16;
typedef __attribute__((ext_vector_type(8))) short short8v;  // 8 bf16 = 4 VGPRs
typedef __attribute__((ext_vector_type(4))) float f32x4;
typedef __attribute__((ext_vector_type(4))) u32 uint4v;

// readlane: value from lane `sl` (wave-uniform index ok), bitcast through uint
__device__ __forceinline__ float rl_f32(float x, int sl) {
    return __uint_as_float(__builtin_amdgcn_readlane(__float_as_uint(x), sl));
}

// Exact-ish two-term split: f = hi + lo (both bf16 by truncation).
// |f - hi - lo| <= 2^-16 |f|  (trunc hi: <=2^-8; trunc of exact residual: <=2^-8 of that)
// Packs two elements' hi (lo) into one u32, low element in low half.
__device__ __forceinline__ void split_pk(float f0, float f1, u32& hpk, u32& lpk) {
    const u32 u0 = __float_as_uint(f0), u1 = __float_as_uint(f1);
    const u32 t1 = u1 & 0xffff0000u;
    hpk = (u0 >> 16) | t1;
    const float fl0 = f0 - __uint_as_float(u0 & 0xffff0000u);
    const float fl1 = f1 - __uint_as_float(t1);
    lpk = (__float_as_uint(fl0) >> 16) | (__float_as_uint(fl1) & 0xffff0000u);
}

// ---------------------------------------------------------------------------
// Kernel 0: one-shot W split fp32 -> bf16 hi/lo (RTNE), padded to 32 rows.
// Also zeroes the loss accumulator out[0] (re-zeroed every graph replay).
// ---------------------------------------------------------------------------
__global__ __launch_bounds__(256) void wcvt_kernel(const float* __restrict__ W,
                                                   u16* __restrict__ Wh,
                                                   u16* __restrict__ Wl,
                                                   float* __restrict__ out) {
    const int i = blockIdx.x * 256 + threadIdx.x;       // 0 .. 32*1024-1
    if (i == 0) out[0] = 0.f;
    const int t = i >> 10;
    const float f = (t < T_) ? W[i] : 0.f;              // W is [24][1024]; i = t*1024+k
    const u32 u = __float_as_uint(f);
    const u32 rh = u + 0x7fffu + ((u >> 16) & 1u);      // RTNE
    const u16 hb = (u16)(rh >> 16);
    const float fh = __uint_as_float((u32)hb << 16);
    const float fl = f - fh;
    const u32 u2 = __float_as_uint(fl);
    const u32 rl2 = u2 + 0x7fffu + ((u2 >> 16) & 1u);
    Wh[i] = hb;
    Wl[i] = (u16)(rl2 >> 16);
}

// ---------------------------------------------------------------------------
// Kernel 1: emission GEMM via MFMA (bf16 hi/lo split, fp32-grade accuracy).
// Wave = one 16-row M-tile x all 24(->32) cols. No LDS: A has zero cross-wave
// reuse (N fits in-wave), so fragments load straight from global, coalesced
// 32B/lane. 3 MFMAs per (Nfrag,Kstep): fh*wh + fh*wl + fl*wh.
// A/B use the SAME (group,elem)->k map, so any k-permutation cancels.
// C/D map (m89-verified): col = lane&15, row = (lane>>4)*4 + reg.
// ---------------------------------------------------------------------------
__global__ __launch_bounds__(256) void gemm_kernel(const float* __restrict__ feats,
                                                   const u16* __restrict__ Wh,
                                                   const u16* __restrict__ Wl,
                                                   const float* __restrict__ bias,
                                                   float* __restrict__ emission) {
    const int tid  = threadIdx.x;
    const int lane = tid & 63;
    const int wv   = tid >> 6;            // wave 0..3
    const int r16  = lane & 15;           // A-row in tile / output col
    const int g    = lane >> 4;           // 0..3 (k-group)
    const int mtile = blockIdx.x * 4 + wv;

    const float* ap  = feats + ((long)mtile * 16 + r16) * H_ + g * 8;
    const u16* bh0p = Wh + r16 * H_ + g * 8;           // Nfrag0: cols 0..15
    const u16* bl0p = Wl + r16 * H_ + g * 8;
    const u16* bh1p = Wh + (r16 + 16) * H_ + g * 8;    // Nfrag1: cols 16..31 (24..31 zero-padded)
    const u16* bl1p = Wl + (r16 + 16) * H_ + g * 8;

    f32x4 acc0 = {0.f, 0.f, 0.f, 0.f};
    f32x4 acc1 = {0.f, 0.f, 0.f, 0.f};

#pragma unroll 4
    for (int kk = 0; kk < H_ / 32; ++kk) {
        const int ko = kk * 32;
        const float4 a0 = *(const float4*)(ap + ko);
        const float4 a1 = *(const float4*)(ap + ko + 4);
        const short8v bh0 = *(const short8v*)(bh0p + ko);
        const short8v bl0 = *(const short8v*)(bl0p + ko);
        const short8v bh1 = *(const short8v*)(bh1p + ko);
        const short8v bl1 = *(const short8v*)(bl1p + ko);

        u32 h0, l0, h1, l1, h2, l2, h3, l3;
        split_pk(a0.x, a0.y, h0, l0);
        split_pk(a0.z, a0.w, h1, l1);
        split_pk(a1.x, a1.y, h2, l2);
        split_pk(a1.z, a1.w, h3, l3);
        const uint4v hv = {h0, h1, h2, h3};
        const uint4v lv = {l0, l1, l2, l3};
        const short8v ah = __builtin_bit_cast(short8v, hv);
        const short8v al = __builtin_bit_cast(short8v, lv);

        acc0 = __builtin_amdgcn_mfma_f32_16x16x32_bf16(al, bh0, acc0, 0, 0, 0);
        acc0 = __builtin_amdgcn_mfma_f32_16x16x32_bf16(ah, bl0, acc0, 0, 0, 0);
        acc0 = __builtin_amdgcn_mfma_f32_16x16x32_bf16(ah, bh0, acc0, 0, 0, 0);
        acc1 = __builtin_amdgcn_mfma_f32_16x16x32_bf16(al, bh1, acc1, 0, 0, 0);
        acc1 = __builtin_amdgcn_mfma_f32_16x16x32_bf16(ah, bl1, acc1, 0, 0, 0);
        acc1 = __builtin_amdgcn_mfma_f32_16x16x32_bf16(ah, bh1, acc1, 0, 0, 0);
    }

    // epilogue: C/D layout col=lane&15, row=4*(lane>>4)+reg
    const float b0 = bias[r16];
    const float b1 = (r16 + 16 < T_) ? bias[r16 + 16] : 0.f;
    float* op = emission + ((long)mtile * 16 + g * 4) * T_;
#pragma unroll
    for (int r = 0; r < 4; ++r) {
        op[r * T_ + r16] = acc0[r] + b0;
        if (r16 + 16 < T_) op[r * T_ + r16 + 16] = acc1[r] + b1;
    }
}

// ---------------------------------------------------------------------------
// Kernel 2: forward algorithm (unchanged math) + folded-in gold-path score and
// finalize: each block b atomically adds (logZ_b - score_b)/B to out[0].
// ---------------------------------------------------------------------------
#define DECL_E(i) const float E##i = __expf(trans[(i) * T_ + jj]);
#define FMA4(i0, i1, i2, i3)                                                   \
    s0 = fmaf(rl_f32(q, i0), E##i0, s0);                                       \
    s1 = fmaf(rl_f32(q, i1), E##i1, s1);                                       \
    s2 = fmaf(rl_f32(q, i2), E##i2, s2);                                       \
    s3 = fmaf(rl_f32(q, i3), E##i3, s3);

__global__ __launch_bounds__(64, 1) void scan_kernel(const float* __restrict__ emission,
                                                     const int* __restrict__ target,
                                                     const int* __restrict__ mask,
                                                     const float* __restrict__ trans,
                                                     float* __restrict__ out) {
    const int b = blockIdx.x;
    const int j = threadIdx.x;          // math lanes j<24; others dummies
    const int jj = j < 24 ? j : 23;

    const float* em = emission + (long)b * S_ * T_;
    const int* mk = mask + b * S_;

    // len = sum(mask row) (prefix-contiguous by construction)
    int mc = 0;
#pragma unroll
    for (int k = 0; k < 8; ++k) mc += mk[j + k * 64];
#pragma unroll
    for (int off = 32; off; off >>= 1) mc += __shfl_xor(mc, off);
    const int len = __builtin_amdgcn_readfirstlane(mc);

    DECL_E(0)  DECL_E(1)  DECL_E(2)  DECL_E(3)  DECL_E(4)  DECL_E(5)
    DECL_E(6)  DECL_E(7)  DECL_E(8)  DECL_E(9)  DECL_E(10) DECL_E(11)
    DECL_E(12) DECL_E(13) DECL_E(14) DECL_E(15) DECL_E(16) DECL_E(17)
    DECL_E(18) DECL_E(19) DECL_E(20) DECL_E(21) DECL_E(22) DECL_E(23)

    float q = (j < 24) ? __expf(em[j]) : 0.f;
    float C = 0.f;

    // prefetch ring of RAW emissions, depth 8 (load leads consume by 8 steps)
    float lb[8];
#pragma unroll
    for (int k = 0; k < 8; ++k) lb[k] = em[(1 + k) * T_ + jj];

    for (int sb = 1; sb < S_; sb += 16) {
#pragma unroll
        for (int k = 0; k < 16; ++k) {
            const int s = sb + k;
            const float X = __expf(lb[k & 7]);   // loaded 8 steps ago: no stall
            const int sp = s + 8;
            lb[k & 7] = (sp < S_) ? em[sp * T_ + jj] : 0.f;

            if (s < len) {               // uniform branch (len in SGPR)
                float s0 = 0.f, s1 = 0.f, s2 = 0.f, s3 = 0.f;
                FMA4(0, 1, 2, 3)
                FMA4(4, 5, 6, 7)
                FMA4(8, 9, 10, 11)
                FMA4(12, 13, 14, 15)
                FMA4(16, 17, 18, 19)
                FMA4(20, 21, 22, 23)
                q = ((s0 + s1) + (s2 + s3)) * X;
            }
        }
        // window renormalization (1/16 amortized on the chain)
        const float r = rl_f32(q, 0);
        q *= (1.0f / r);
        C += __logf(r);
    }

    float ex = (j < 24) ? q : 0.f;
#pragma unroll
    for (int off = 32; off; off >>= 1) ex += __shfl_down(ex, off);

    // ---- folded gold-path score (was score_kernel): all 64 lanes ----
    float ssum = 0.f;
#pragma unroll
    for (int kk = 0; kk < S_ / 64; ++kk) {
        const int s = j + kk * 64;
        if (mk[s]) {
            const int tg = target[b * S_ + s];
            float v = em[s * T_ + tg];
            if (s > 0) v += trans[target[b * S_ + s - 1] * T_ + tg];
            ssum += v;
        }
    }
#pragma unroll
    for (int off = 32; off; off >>= 1) ssum += __shfl_down(ssum, off);

    if (j == 0) {
        const float logZ = C + __logf(ex);
        atomicAdd(out, (logZ - ssum) * (1.0f / B_));   // loss = mean(logZ - score)
    }
}

extern "C" void kernel_launch(void* const* d_in, const int* in_sizes, int n_in,
                              void* d_out, int out_size, void* d_ws, size_t ws_size,
                              hipStream_t stream) {
    const float* feats  = (const float*)d_in[0];
    const int*   target = (const int*)d_in[1];
    const int*   mask   = (const int*)d_in[2];
    const float* W      = (const float*)d_in[3];
    const float* bias   = (const float*)d_in[4];
    const float* trans  = (const float*)d_in[5];

    float* out = (float*)d_out;
    float* emission = out + 1;            // output 1, written in place
    u16* Wh = (u16*)d_ws;                 // 32*1024 bf16 = 64 KB
    u16* Wl = Wh + TP_ * H_;              // 64 KB

    wcvt_kernel<<<(TP_ * H_) / 256, 256, 0, stream>>>(W, Wh, Wl, out);
    gemm_kernel<<<512, 256, 0, stream>>>(feats, Wh, Wl, bias, emission);
    scan_kernel<<<64, 64, 0, stream>>>(emission, target, mask, trans, out);
}